// Round 1
// baseline (253.777 us; speedup 1.0000x reference)
//
#include <hip/hip_runtime.h>

#define S_LEN 2048
#define NH 16
#define HD 64
#define DMODEL 1024

typedef __attribute__((ext_vector_type(8))) short bf16x8;
typedef __attribute__((ext_vector_type(4))) float f32x4;

__device__ inline unsigned short f2bf(float f) {
  union { float f; unsigned u; } v; v.f = f;
  unsigned r = v.u + 0x7FFFu + ((v.u >> 16) & 1u);
  return (unsigned short)(r >> 16);
}

__device__ inline void async16(void* lds, const void* g) {
  __builtin_amdgcn_global_load_lds((__attribute__((address_space(1))) void*)(g),
                                   (__attribute__((address_space(3))) void*)(lds),
                                   16, 0, 0);
}

// ---------------- prep: fp32->bf16 casts + bias table (exp2-domain) ----------------
// blocks [0,8192): cast x, qkv_w, o_w.  blocks [8192,8208): build bias_rel[h][4096].
__global__ __launch_bounds__(256) void prep_kernel(
    const float* __restrict__ x, const float* __restrict__ emb,
    const float* __restrict__ qkv_w, const float* __restrict__ o_w,
    unsigned short* __restrict__ xb, unsigned short* __restrict__ wb,
    unsigned short* __restrict__ ob, float* __restrict__ biasg) {
  if (blockIdx.x >= 8192) {
    int h = blockIdx.x - 8192;
    for (int i = threadIdx.x; i < 4095; i += 256) {
      int rel = i - 2047;                       // rel = k - q
      int a = rel < 0 ? -rel : rel;
      int bucket;
      if (a < 8) bucket = a;
      else bucket = 8 + (a >= 12) + (a >= 16) + (a >= 23) + (a >= 32) +
                        (a >= 46) + (a >= 64) + (a >= 91);
      if (rel > 0) bucket += 16;
      biasg[h * 4096 + i] = emb[bucket * NH + h] * 1.4426950408889634f;
    }
    return;
  }
  const int NX = 2 * S_LEN * DMODEL / 4;   // 1048576 float4s
  const int NW = 3 * NH * HD * DMODEL / 4; // 786432
  int j = blockIdx.x * 256 + threadIdx.x;
  const float* s; unsigned short* d;
  if (j < NX)            { s = x;     d = xb; }
  else if (j < NX + NW)  { j -= NX;      s = qkv_w; d = wb; }
  else                   { j -= NX + NW; s = o_w;   d = ob; }
  float4 v = ((const float4*)s)[j];
  ushort4 p;
  p.x = f2bf(v.x); p.y = f2bf(v.y); p.z = f2bf(v.z); p.w = f2bf(v.w);
  ((ushort4*)d)[j] = p;
}

// ---------------- QKV GEMM: [4096,1024]bf16 @ [3072,1024]^T -> Q,K,Vt ----------------
__global__ __launch_bounds__(256) void qkv_gemm_kernel(
    const unsigned short* __restrict__ xb, const unsigned short* __restrict__ wb,
    unsigned short* __restrict__ Qg, unsigned short* __restrict__ Kg,
    unsigned short* __restrict__ Vtg) {
  __shared__ __align__(16) char smem[32768];
  char* As = smem;           // [2][8192]
  char* Bs = smem + 16384;   // [2][8192]
  int bid = blockIdx.x;
  int swz = (bid & 7) * 96 + (bid >> 3);      // 768 % 8 == 0, bijective
  int bm = swz / 24, bn = swz % 24;
  const int tid = threadIdx.x, lane = tid & 63, wave = tid >> 6;
  const int wr = wave >> 1, wc = wave & 1, lg = lane >> 4, li = lane & 15;
  const char* Ag = (const char*)xb;
  const char* Bg = (const char*)wb;

  f32x4 acc[4][4];
#pragma unroll
  for (int i = 0; i < 4; ++i)
#pragma unroll
    for (int j = 0; j < 4; ++j) acc[i][j] = (f32x4){0.f, 0.f, 0.f, 0.f};

  auto stage = [&](int buf, int kt) {
#pragma unroll
    for (int r = 0; r < 2; ++r) {
      int c = wave * 2 + r;                 // wave-uniform chunk id
      int linear = c * 1024 + lane * 16;
      int row = linear >> 6;
      int cb = (linear & 63) ^ ((row & 3) << 4);   // pre-swizzled source
      async16(As + buf * 8192 + c * 1024,
              Ag + (size_t)(bm * 128 + row) * 2048 + kt * 64 + cb);
      async16(Bs + buf * 8192 + c * 1024,
              Bg + (size_t)(bn * 128 + row) * 2048 + kt * 64 + cb);
    }
  };

  stage(0, 0);
  __syncthreads();
  for (int kt = 0; kt < 32; ++kt) {
    int cur = kt & 1;
    if (kt < 31) stage(cur ^ 1, kt + 1);
    const char* Ab = As + cur * 8192;
    const char* Bb = Bs + cur * 8192;
    bf16x8 af[4], bfr[4];
#pragma unroll
    for (int i = 0; i < 4; ++i) {
      int ra = wr * 64 + i * 16 + li;
      af[i] = *(const bf16x8*)(Ab + ra * 64 + ((lg * 16) ^ ((ra & 3) << 4)));
      int rb = wc * 64 + i * 16 + li;
      bfr[i] = *(const bf16x8*)(Bb + rb * 64 + ((lg * 16) ^ ((rb & 3) << 4)));
    }
#pragma unroll
    for (int i = 0; i < 4; ++i)
#pragma unroll
      for (int j = 0; j < 4; ++j)
        acc[i][j] = __builtin_amdgcn_mfma_f32_16x16x32_bf16(af[i], bfr[j], acc[i][j], 0, 0, 0);
    __syncthreads();
  }

  int n0 = bn * 128 + wc * 64;   // wave-uniform
  int which = n0 >> 10;          // 0=Q 1=K 2=V
  int h = (n0 >> 6) & 15;
  if (which < 2) {
    unsigned short* dst = (which == 0) ? Qg : Kg;
    float scl = (which == 0) ? 0.18033688011112042f : 1.0f;  // 0.125*log2(e) folded into Q
#pragma unroll
    for (int i = 0; i < 4; ++i)
#pragma unroll
      for (int j = 0; j < 4; ++j)
#pragma unroll
        for (int r = 0; r < 4; ++r) {
          int mr = bm * 128 + wr * 64 + i * 16 + lg * 4 + r;
          int b = mr >> 11, sIdx = mr & 2047;
          int d = j * 16 + li;
          dst[(((size_t)(b * NH + h)) * S_LEN + sIdx) * HD + d] = f2bf(acc[i][j][r] * scl);
        }
  } else {
    // V: transpose 64x64 wave tile through LDS (reuse smem; per-wave region) -> Vt[bh][d][s]
    char* T = smem + wave * 8192;
#pragma unroll
    for (int i = 0; i < 4; ++i)
#pragma unroll
      for (int j = 0; j < 4; ++j)
#pragma unroll
        for (int r = 0; r < 4; ++r) {
          int sl = i * 16 + lg * 4 + r;     // local s 0..63
          int dd = j * 16 + li;             // local d 0..63
          *(unsigned short*)(T + dd * 128 + ((sl * 2) ^ ((dd & 7) << 4))) = f2bf(acc[i][j][r]);
        }
    int m0 = bm * 128 + wr * 64;
    int b = m0 >> 11, s0 = m0 & 2047;
#pragma unroll
    for (int r2 = 0; r2 < 8; ++r2) {
      int linear = r2 * 1024 + lane * 16;
      int dd = linear >> 7;
      int ts = linear & 127;               // true s-byte within the 64-row tile
      bf16x8 v = *(const bf16x8*)(T + dd * 128 + (ts ^ ((dd & 7) << 4)));
      char* dstb = (char*)Vtg + (((size_t)(b * NH + h) * HD + dd) * S_LEN + s0) * 2 + ts;
      *(bf16x8*)dstb = v;
    }
  }
}

// ---------------- flash attention with T5 bias ----------------
__global__ __launch_bounds__(256) void attn_kernel(
    const unsigned short* __restrict__ Qg, const unsigned short* __restrict__ Kg,
    const unsigned short* __restrict__ Vtg, const float* __restrict__ biasg,
    unsigned short* __restrict__ aout) {
  __shared__ __align__(16) char Kl[2][8192];
  __shared__ __align__(16) char Vl[2][8192];
  __shared__ float biasl[2208];
  __shared__ __align__(16) char Pl[4][4608];   // per-wave [32][72] bf16, 144B rows

  int bid = blockIdx.x;
  int swz = (bid & 7) * 64 + (bid >> 3);       // 512 % 8 == 0, bijective
  int bh = swz >> 4;
  int qt = swz & 15;
  int b = bh >> 4, h = bh & 15;
  int qbase = qt * 128;
  const int tid = threadIdx.x, lane = tid & 63, wave = tid >> 6;
  const int lg = lane >> 4, li = lane & 15;
  const int qw = wave * 32;

  const char* Kbh = (const char*)(Kg + (size_t)bh * S_LEN * HD);
  const char* Vbh = (const char*)(Vtg + (size_t)bh * HD * S_LEN);
  const unsigned short* Qbh = Qg + (size_t)bh * S_LEN * HD;

  // stage bias strip: strip[i] = biasg[h][i + 1920 - qbase], i in [0,2175)
  for (int i = tid; i < 2208; i += 256)
    biasl[i] = (i < 2175) ? biasg[h * 4096 + i + 1920 - qbase] : 0.f;

  bf16x8 qf[2][2];
#pragma unroll
  for (int m = 0; m < 2; ++m)
#pragma unroll
    for (int kk = 0; kk < 2; ++kk)
      qf[m][kk] = *(const bf16x8*)(Qbh + (size_t)(qbase + qw + m * 16 + li) * HD + kk * 32 + lg * 8);

  f32x4 Oa[2][4];
  float mrow[2][4], lrow[2][4];
#pragma unroll
  for (int m = 0; m < 2; ++m) {
#pragma unroll
    for (int dt = 0; dt < 4; ++dt) Oa[m][dt] = (f32x4){0.f, 0.f, 0.f, 0.f};
#pragma unroll
    for (int r = 0; r < 4; ++r) { mrow[m][r] = -1e30f; lrow[m][r] = 0.f; }
  }

  auto stage = [&](int buf, int kt) {
#pragma unroll
    for (int r = 0; r < 2; ++r) {
      int c = wave * 2 + r;
      int linear = c * 1024 + lane * 16;
      int row = linear >> 7;                       // 0..63
      int sb = (linear & 127) ^ ((row & 7) << 4);  // pre-swizzled source
      async16(Kl[buf] + c * 1024, Kbh + (size_t)(kt * 64 + row) * 128 + sb);
      async16(Vl[buf] + c * 1024, Vbh + (size_t)row * 4096 + kt * 128 + sb);
    }
  };

  stage(0, 0);
  __syncthreads();

  for (int kt = 0; kt < 32; ++kt) {
    int cur = kt & 1;
    if (kt < 31) stage(cur ^ 1, kt + 1);

    // ---- QK^T (scores pre-scaled via Q; exp2 domain) ----
    f32x4 sc[2][4];
#pragma unroll
    for (int m = 0; m < 2; ++m)
#pragma unroll
      for (int nt = 0; nt < 4; ++nt) sc[m][nt] = (f32x4){0.f, 0.f, 0.f, 0.f};
#pragma unroll
    for (int kk = 0; kk < 2; ++kk)
#pragma unroll
      for (int nt = 0; nt < 4; ++nt) {
        int row = nt * 16 + li;
        bf16x8 kf = *(const bf16x8*)(Kl[cur] + row * 128 +
                                     ((kk * 64 + lg * 16) ^ ((row & 7) << 4)));
#pragma unroll
        for (int m = 0; m < 2; ++m)
          sc[m][nt] = __builtin_amdgcn_mfma_f32_16x16x32_bf16(qf[m][kk], kf, sc[m][nt], 0, 0, 0);
      }

    // ---- bias + online softmax (wave-parallel) ----
#pragma unroll
    for (int m = 0; m < 2; ++m) {
      float sv[4][4];
#pragma unroll
      for (int nt = 0; nt < 4; ++nt) {
        int base = kt * 64 + nt * 16 + li + 127 - (qw + m * 16 + lg * 4);
#pragma unroll
        for (int r = 0; r < 4; ++r)
          sv[nt][r] = sc[m][nt][r] + biasl[base - r];
      }
      float csc[4];
      float pr[4][4];
#pragma unroll
      for (int r = 0; r < 4; ++r) {
        float mx = fmaxf(fmaxf(sv[0][r], sv[1][r]), fmaxf(sv[2][r], sv[3][r]));
#pragma unroll
        for (int off = 1; off < 16; off <<= 1)
          mx = fmaxf(mx, __shfl_xor(mx, off, 64));
        float mnew = fmaxf(mrow[m][r], mx);
        float c = exp2f(mrow[m][r] - mnew);
        mrow[m][r] = mnew;
        csc[r] = c;
        float ps = 0.f;
#pragma unroll
        for (int nt = 0; nt < 4; ++nt) {
          float p = exp2f(sv[nt][r] - mnew);
          pr[nt][r] = p;
          ps += p;
        }
        lrow[m][r] = lrow[m][r] * c + ps;
      }
#pragma unroll
      for (int dt = 0; dt < 4; ++dt)
#pragma unroll
        for (int r = 0; r < 4; ++r)
          Oa[m][dt][r] *= csc[r];
#pragma unroll
      for (int nt = 0; nt < 4; ++nt)
#pragma unroll
        for (int r = 0; r < 4; ++r) {
          int prow = m * 16 + lg * 4 + r;
          *(unsigned short*)(Pl[wave] + prow * 144 + (nt * 16 + li) * 2) = f2bf(pr[nt][r]);
        }
    }

    // ---- PV ----
#pragma unroll
    for (int kk = 0; kk < 2; ++kk) {
      bf16x8 pa[2];
#pragma unroll
      for (int m = 0; m < 2; ++m)
        pa[m] = *(const bf16x8*)(Pl[wave] + (m * 16 + li) * 144 + (kk * 32 + lg * 8) * 2);
#pragma unroll
      for (int dt = 0; dt < 4; ++dt) {
        int row = dt * 16 + li;
        bf16x8 vf = *(const bf16x8*)(Vl[cur] + row * 128 +
                                     ((kk * 64 + lg * 16) ^ ((row & 7) << 4)));
#pragma unroll
        for (int m = 0; m < 2; ++m)
          Oa[m][dt] = __builtin_amdgcn_mfma_f32_16x16x32_bf16(pa[m], vf, Oa[m][dt], 0, 0, 0);
      }
    }
    __syncthreads();
  }

  // ---- finalize: normalize and store a[b][s][h*64+d] (bf16) ----
#pragma unroll
  for (int m = 0; m < 2; ++m) {
    float inv[4];
#pragma unroll
    for (int r = 0; r < 4; ++r) {
      float t = lrow[m][r];
#pragma unroll
      for (int off = 1; off < 16; off <<= 1)
        t += __shfl_xor(t, off, 64);
      inv[r] = 1.0f / t;
    }
#pragma unroll
    for (int dt = 0; dt < 4; ++dt)
#pragma unroll
      for (int r = 0; r < 4; ++r) {
        int srow = qbase + qw + m * 16 + lg * 4 + r;
        aout[((size_t)b * S_LEN + srow) * DMODEL + h * HD + dt * 16 + li] =
            f2bf(Oa[m][dt][r] * inv[r]);
      }
  }
}

// ---------------- O projection: [4096,1024]bf16 @ [1024,1024]^T -> fp32 out ----------------
__global__ __launch_bounds__(256) void oproj_gemm_kernel(
    const unsigned short* __restrict__ ab, const unsigned short* __restrict__ ob,
    float* __restrict__ out) {
  __shared__ __align__(16) char smem[32768];
  char* As = smem;
  char* Bs = smem + 16384;
  int bid = blockIdx.x;
  int swz = (bid & 7) * 32 + (bid >> 3);   // 256 % 8 == 0
  int bm = swz >> 3, bn = swz & 7;
  const int tid = threadIdx.x, lane = tid & 63, wave = tid >> 6;
  const int wr = wave >> 1, wc = wave & 1, lg = lane >> 4, li = lane & 15;
  const char* Ag = (const char*)ab;
  const char* Bg = (const char*)ob;

  f32x4 acc[4][4];
#pragma unroll
  for (int i = 0; i < 4; ++i)
#pragma unroll
    for (int j = 0; j < 4; ++j) acc[i][j] = (f32x4){0.f, 0.f, 0.f, 0.f};

  auto stage = [&](int buf, int kt) {
#pragma unroll
    for (int r = 0; r < 2; ++r) {
      int c = wave * 2 + r;
      int linear = c * 1024 + lane * 16;
      int row = linear >> 6;
      int cb = (linear & 63) ^ ((row & 3) << 4);
      async16(As + buf * 8192 + c * 1024,
              Ag + (size_t)(bm * 128 + row) * 2048 + kt * 64 + cb);
      async16(Bs + buf * 8192 + c * 1024,
              Bg + (size_t)(bn * 128 + row) * 2048 + kt * 64 + cb);
    }
  };

  stage(0, 0);
  __syncthreads();
  for (int kt = 0; kt < 32; ++kt) {
    int cur = kt & 1;
    if (kt < 31) stage(cur ^ 1, kt + 1);
    const char* Ab = As + cur * 8192;
    const char* Bb = Bs + cur * 8192;
    bf16x8 af[4], bfr[4];
#pragma unroll
    for (int i = 0; i < 4; ++i) {
      int ra = wr * 64 + i * 16 + li;
      af[i] = *(const bf16x8*)(Ab + ra * 64 + ((lg * 16) ^ ((ra & 3) << 4)));
      int rb = wc * 64 + i * 16 + li;
      bfr[i] = *(const bf16x8*)(Bb + rb * 64 + ((lg * 16) ^ ((rb & 3) << 4)));
    }
#pragma unroll
    for (int i = 0; i < 4; ++i)
#pragma unroll
      for (int j = 0; j < 4; ++j)
        acc[i][j] = __builtin_amdgcn_mfma_f32_16x16x32_bf16(af[i], bfr[j], acc[i][j], 0, 0, 0);
    __syncthreads();
  }

#pragma unroll
  for (int i = 0; i < 4; ++i)
#pragma unroll
    for (int j = 0; j < 4; ++j)
#pragma unroll
      for (int r = 0; r < 4; ++r) {
        int mr = bm * 128 + wr * 64 + i * 16 + lg * 4 + r;
        int n = bn * 128 + wc * 64 + j * 16 + li;
        out[(size_t)mr * DMODEL + n] = acc[i][j][r];
      }
}

// ---------------- host ----------------
extern "C" void kernel_launch(void* const* d_in, const int* in_sizes, int n_in,
                              void* d_out, int out_size, void* d_ws, size_t ws_size,
                              hipStream_t stream) {
  const float* x     = (const float*)d_in[0];
  const float* emb   = (const float*)d_in[1];
  const float* qkv_w = (const float*)d_in[2];
  const float* o_w   = (const float*)d_in[3];
  char* ws = (char*)d_ws;
  unsigned short* xb = (unsigned short*)(ws);
  unsigned short* wb = (unsigned short*)(ws + 8388608);
  unsigned short* ob = (unsigned short*)(ws + 14680064);
  unsigned short* Qg = (unsigned short*)(ws + 16777216);
  unsigned short* Kg = (unsigned short*)(ws + 25165824);
  unsigned short* Vt = (unsigned short*)(ws + 33554432);
  unsigned short* ab = (unsigned short*)(ws + 41943040);
  float* biasg       = (float*)(ws + 50331648);
  float* out = (float*)d_out;

  prep_kernel<<<8208, 256, 0, stream>>>(x, emb, qkv_w, o_w, xb, wb, ob, biasg);
  qkv_gemm_kernel<<<768, 256, 0, stream>>>(xb, wb, Qg, Kg, Vt);
  attn_kernel<<<512, 256, 0, stream>>>(Qg, Kg, Vt, biasg, ab);
  oproj_gemm_kernel<<<256, 256, 0, stream>>>(ab, ob, out);
}